// Round 10
// baseline (227.317 us; speedup 1.0000x reference)
//
#include <hip/hip_runtime.h>

// ---------------- problem constants ----------------
#define EMBED 1024
#define NHEAD 16
#define HDIM  64
#define BATCH 2
#define SEQ   2048
#define ROWS  (BATCH*SEQ)   // 4096

typedef __bf16 bf16x8 __attribute__((ext_vector_type(8)));
typedef float  f32x4  __attribute__((ext_vector_type(4)));
typedef float  f32x16 __attribute__((ext_vector_type(16)));
typedef unsigned short u16x8 __attribute__((ext_vector_type(8)));
typedef unsigned short u16x4 __attribute__((ext_vector_type(4)));

__device__ __forceinline__ unsigned short f2bf(float f) {
    unsigned int u = __float_as_uint(f);
    u += 0x7FFFu + ((u >> 16) & 1u);          // round-to-nearest-even
    return (unsigned short)(u >> 16);
}
__device__ __forceinline__ f32x4 zero4() { f32x4 z = {0.f, 0.f, 0.f, 0.f}; return z; }

// pack two f32 -> bf16 pair in one instruction (RNE)
__device__ __forceinline__ unsigned int cvtpk_bf16(float lo, float hi) {
    unsigned int r;
    asm("v_cvt_pk_bf16_f32 %0, %1, %2" : "=v"(r) : "v"(lo), "v"(hi));
    return r;
}
// new_a = [a.row0 | b.row0], new_b = [a.row1 | b.row1]  (rows = lane<32 / lane>=32)
__device__ __forceinline__ void pl32swap(unsigned int &a, unsigned int &b) {
    asm("v_permlane32_swap_b32 %0, %1" : "+v"(a), "+v"(b));
}
// hardware exp2 (v_exp_f32: D = 2^S0)
__device__ __forceinline__ float exp2_hw(float x) {
    float r;
    asm("v_exp_f32 %0, %1" : "=v"(r) : "v"(x));
    return r;
}

// async global->LDS, 16B per lane; lds dest is wave-uniform base (+lane*16 by HW)
__device__ __forceinline__ void gl_lds16(const unsigned short* g, unsigned short* l) {
    __builtin_amdgcn_global_load_lds(
        (const __attribute__((address_space(1))) void*)g,
        (__attribute__((address_space(3))) void*)l, 16, 0, 0);
}

// ---------------- fused f32 -> bf16 cast for q/k/v (8 elems/thread, 16B stores) ----------------
__global__ __launch_bounds__(256) void cvt3_kernel(const float* __restrict__ q,
                                                   const float* __restrict__ k,
                                                   const float* __restrict__ v,
                                                   unsigned short* __restrict__ qo,
                                                   unsigned short* __restrict__ ko,
                                                   unsigned short* __restrict__ vo) {
    const float* in; unsigned short* out;
    if (blockIdx.y == 0)      { in = q; out = qo; }
    else if (blockIdx.y == 1) { in = k; out = ko; }
    else                      { in = v; out = vo; }
    int i = (blockIdx.x * 256 + threadIdx.x) * 8;
    float4 a = *(const float4*)(in + i);
    float4 b = *(const float4*)(in + i + 4);
    u16x8 o = {f2bf(a.x), f2bf(a.y), f2bf(a.z), f2bf(a.w),
               f2bf(b.x), f2bf(b.y), f2bf(b.z), f2bf(b.w)};
    *(u16x8*)(out + i) = o;
}

// ---------------- fused W [K,N] f32 -> Wt [N,K] bf16 for 4 weights ----------------
__global__ __launch_bounds__(256) void transpose4_kernel(const float* __restrict__ w0,
                                                         const float* __restrict__ w1,
                                                         const float* __restrict__ w2,
                                                         const float* __restrict__ w3,
                                                         unsigned short* __restrict__ o0,
                                                         unsigned short* __restrict__ o1,
                                                         unsigned short* __restrict__ o2,
                                                         unsigned short* __restrict__ o3) {
    const float* in; unsigned short* out;
    if (blockIdx.z == 0)      { in = w0; out = o0; }
    else if (blockIdx.z == 1) { in = w1; out = o1; }
    else if (blockIdx.z == 2) { in = w2; out = o2; }
    else                      { in = w3; out = o3; }
    __shared__ float tile[32][33];
    int tx = threadIdx.x, ty = threadIdx.y;              // 32 x 8
    int x = blockIdx.x * 32 + tx;
    int y0 = blockIdx.y * 32 + ty;
#pragma unroll
    for (int r = 0; r < 4; ++r)
        tile[ty + 8 * r][tx] = in[(size_t)(y0 + 8 * r) * EMBED + x];
    __syncthreads();
    int ox = blockIdx.y * 32 + tx;
    int oy = blockIdx.x * 32 + ty;
#pragma unroll
    for (int r = 0; r < 4; ++r)
        out[(size_t)(oy + 8 * r) * EMBED + ox] = f2bf(tile[tx][ty + 8 * r]);
}

// ---------------- 128x128 bf16 GEMM, ring-3 single-barrier K-loop (T3/T4) ------
__global__ __launch_bounds__(256, 2) void gemm_qkv_kernel(
    const unsigned short* __restrict__ qb, const unsigned short* __restrict__ kb,
    const unsigned short* __restrict__ vb,
    const unsigned short* __restrict__ Wqt, const unsigned short* __restrict__ Wkt,
    const unsigned short* __restrict__ Wvt,
    const float* __restrict__ bq, const float* __restrict__ bk, const float* __restrict__ bv,
    unsigned short* __restrict__ Qp, unsigned short* __restrict__ Kp,
    unsigned short* __restrict__ Vtb) {
    __shared__ unsigned short smem[24576];   // A slots [0,12288) x3, B slots [12288,24576) x3
                                             // epilogue: reused as 64x136 transpose tile
    const unsigned short *A, *Bt; const float* bias; unsigned short* outp; int mode; float osc;
    if (blockIdx.z == 0)      { A = qb; Bt = Wqt; bias = bq; outp = Qp;  mode = 0; osc = 0.18033688f; }
    else if (blockIdx.z == 1) { A = kb; Bt = Wkt; bias = bk; outp = Kp;  mode = 0; osc = 1.0f; }
    else                      { A = vb; Bt = Wvt; bias = bv; outp = Vtb; mode = 1; osc = 1.0f; }

    const int t = threadIdx.x;
    const int m0 = blockIdx.x * 128, n0 = blockIdx.y * 128;
    const int wave = t >> 6, lane = t & 63;
    const int wr = wave >> 1, wc = wave & 1;             // 2x2 wave grid, 64x64 each
    const int lm = lane & 15, lq = lane >> 4;
    const int sr = t >> 2;                               // staging row 0..63
    const int csrc = (t & 3) ^ ((sr >> 1) & 3);          // chunk-XOR swizzle source
    const int pa = lq ^ ((lm >> 1) & 3);                 // fragment chunk position

    const unsigned short* gA = A + (size_t)(m0 + sr) * EMBED + csrc * 8;
    const unsigned short* gB = Bt + (size_t)(n0 + sr) * EMBED + csrc * 8;

    f32x4 acc[4][4];
#pragma unroll
    for (int i = 0; i < 4; ++i)
#pragma unroll
        for (int j = 0; j < 4; ++j) acc[i][j] = zero4();

#define QKV_STAGE(SOFF)                                                      \
    gl_lds16(gA,              smem + (SOFF) + wave * 512);                   \
    gl_lds16(gA + 64 * EMBED, smem + (SOFF) + 2048 + wave * 512);            \
    gl_lds16(gB,              smem + 12288 + (SOFF) + wave * 512);           \
    gl_lds16(gB + 64 * EMBED, smem + 12288 + (SOFF) + 2048 + wave * 512);    \
    gA += 32; gB += 32;

#define QKV_COMP(COFF)                                                                 \
    {                                                                                  \
        bf16x8 af[4], bfr[4];                                                          \
        _Pragma("unroll")                                                              \
        for (int i = 0; i < 4; ++i)                                                    \
            af[i] = *(const bf16x8*)&smem[(COFF) + (wr * 64 + i * 16 + lm) * 32 + pa * 8]; \
        _Pragma("unroll")                                                              \
        for (int j = 0; j < 4; ++j)                                                    \
            bfr[j] = *(const bf16x8*)&smem[12288 + (COFF) + (wc * 64 + j * 16 + lm) * 32 + pa * 8]; \
        _Pragma("unroll")                                                              \
        for (int i = 0; i < 4; ++i)                                                    \
            _Pragma("unroll")                                                          \
            for (int j = 0; j < 4; ++j)                                                \
                acc[i][j] = __builtin_amdgcn_mfma_f32_16x16x32_bf16(af[i], bfr[j], acc[i][j], 0, 0, 0); \
    }

    // prologue: tile0 -> slot0, tile1 -> slot1; ptrs end at tile2
    QKV_STAGE(0)
    QKV_STAGE(4096)

    for (int g = 0; g < 10; ++g) {       // i = 3g, 3g+1, 3g+2  (covers 0..29)
        asm volatile("s_waitcnt vmcnt(4)" ::: "memory");
        __builtin_amdgcn_s_barrier();
        QKV_STAGE(8192)                  // tile i+2 -> slot2
        QKV_COMP(0)
        asm volatile("s_waitcnt vmcnt(4)" ::: "memory");
        __builtin_amdgcn_s_barrier();
        QKV_STAGE(0)                     // -> slot0
        QKV_COMP(4096)
        asm volatile("s_waitcnt vmcnt(4)" ::: "memory");
        __builtin_amdgcn_s_barrier();
        QKV_STAGE(4096)                  // -> slot1
        QKV_COMP(8192)
    }
    // i=30 (slot0, no stage), i=31 (slot1, drain)
    asm volatile("s_waitcnt vmcnt(4)" ::: "memory");
    __builtin_amdgcn_s_barrier();
    QKV_COMP(0)
    asm volatile("s_waitcnt vmcnt(0)" ::: "memory");
    __builtin_amdgcn_s_barrier();
    QKV_COMP(4096)

    const int row = t >> 2, seg = t & 3;     // readback: 64B per thread, coalesced
    if (mode == 0) {
        // out[s][hd]: two passes over m-halves; LDS tile Ct[ml 64][nl 128] (+8 pad)
#pragma unroll
        for (int p = 0; p < 2; ++p) {
            __syncthreads();
            if (wr == p) {
#pragma unroll
                for (int i = 0; i < 4; ++i)
#pragma unroll
                    for (int j = 0; j < 4; ++j) {
                        float bn = bias[n0 + wc * 64 + j * 16 + lm];
                        int nl = wc * 64 + j * 16 + lm;
#pragma unroll
                        for (int r = 0; r < 4; ++r)
                            smem[(i * 16 + lq * 4 + r) * 136 + nl] =
                                f2bf((acc[i][j][r] + bn) * osc);
                    }
            }
            __syncthreads();
            int m = m0 + p * 64 + row;
            int b = m >> 11, sI = m & 2047;
            int ncol = n0 + seg * 32;
            int h = ncol >> 6, hd0 = ncol & 63;
            unsigned short* dst = outp + (((size_t)((b * NHEAD + h) * SEQ + sI)) << 6) + hd0;
            const unsigned short* src = smem + row * 136 + seg * 32;
            *(u16x8*)(dst)      = *(const u16x8*)(src);
            *(u16x8*)(dst + 8)  = *(const u16x8*)(src + 8);
            *(u16x8*)(dst + 16) = *(const u16x8*)(src + 16);
            *(u16x8*)(dst + 24) = *(const u16x8*)(src + 24);
        }
    } else {
        // out[hd][s]: two passes over n-halves; LDS tile Cn[nl 64][ml 128] (+8 pad), packed writes
#pragma unroll
        for (int p = 0; p < 2; ++p) {
            __syncthreads();
            if (wc == p) {
#pragma unroll
                for (int i = 0; i < 4; ++i)
#pragma unroll
                    for (int j = 0; j < 4; ++j) {
                        float bn = bias[n0 + p * 64 + j * 16 + lm];
                        u16x4 pw = {f2bf(acc[i][j][0] + bn), f2bf(acc[i][j][1] + bn),
                                    f2bf(acc[i][j][2] + bn), f2bf(acc[i][j][3] + bn)};
                        *(u16x4*)&smem[(j * 16 + lm) * 136 + wr * 64 + i * 16 + lq * 4] = pw;
                    }
            }
            __syncthreads();
            int n = n0 + p * 64 + row;
            int h = n >> 6, hd = n & 63;
            int b = m0 >> 11;
            int s0 = (m0 & 2047) + seg * 32;
            unsigned short* dst = outp + ((size_t)((b * NHEAD + h) * HDIM + hd)) * SEQ + s0;
            const unsigned short* src = smem + row * 136 + seg * 32;
            *(u16x8*)(dst)      = *(const u16x8*)(src);
            *(u16x8*)(dst + 8)  = *(const u16x8*)(src + 8);
            *(u16x8*)(dst + 16) = *(const u16x8*)(src + 16);
            *(u16x8*)(dst + 24) = *(const u16x8*)(src + 24);
        }
    }
#undef QKV_STAGE
#undef QKV_COMP
}

// ---------------- O-projection GEMM, split-K by 2: M64 x N128 x K512 per block ------
// R10 = R9 resubmit with workspace fix: xbuf1 moved from ws+48MB (extended footprint
// to 64MB — likely OOB crash) to ws+32MB (Qp+Kp region, dead after attn; footprint
// stays at the proven 56MB). grid (64,8,2) = 1024 blocks = 4 blocks/CU — doubles TLP
// on an LDS-read/latency-bound kernel. Race-free f32 partials; ln merges.
__global__ __launch_bounds__(256, 2) void gemm_o_kernel(
    const unsigned short* __restrict__ att, const unsigned short* __restrict__ Wot,
    float* __restrict__ xbuf0, float* __restrict__ xbuf1) {
    __shared__ unsigned short smem[18432];   // A slots [0,6144) x3 (2048 each), B slots [6144,18432) x3 (4096 each)
    const int t = threadIdx.x;
    const int m0 = blockIdx.x * 64, n0 = blockIdx.y * 128;
    const int kz = blockIdx.z;               // k-half: 0 or 1
    float* outp = kz ? xbuf1 : xbuf0;
    const int wave = t >> 6, lane = t & 63;
    const int lm = lane & 15, lq = lane >> 4;
    const int sr = t >> 2;
    const int csrc = (t & 3) ^ ((sr >> 1) & 3);
    const int pa = lq ^ ((lm >> 1) & 3);

    const unsigned short* gA = att + (size_t)(m0 + sr) * EMBED + kz * 512 + csrc * 8;
    const unsigned short* gB = Wot + (size_t)(n0 + sr) * EMBED + kz * 512 + csrc * 8;

    f32x4 acc[4][2];
#pragma unroll
    for (int i = 0; i < 4; ++i)
#pragma unroll
        for (int j = 0; j < 2; ++j) acc[i][j] = zero4();

#define O_STAGE(SA, SB)                                                  \
    gl_lds16(gA,              smem + (SA) + wave * 512);                 \
    gl_lds16(gB,              smem + 6144 + (SB) + wave * 512);          \
    gl_lds16(gB + 64 * EMBED, smem + 6144 + (SB) + 2048 + wave * 512);   \
    gA += 32; gB += 32;

#define O_COMP(SA, SB)                                                                \
    {                                                                                 \
        bf16x8 af[4], bfr[2];                                                         \
        _Pragma("unroll")                                                             \
        for (int i = 0; i < 4; ++i)                                                   \
            af[i] = *(const bf16x8*)&smem[(SA) + (i * 16 + lm) * 32 + pa * 8];        \
        _Pragma("unroll")                                                             \
        for (int j = 0; j < 2; ++j)                                                   \
            bfr[j] = *(const bf16x8*)&smem[6144 + (SB) + (wave * 32 + j * 16 + lm) * 32 + pa * 8]; \
        _Pragma("unroll")                                                             \
        for (int i = 0; i < 4; ++i)                                                   \
            _Pragma("unroll")                                                         \
            for (int j = 0; j < 2; ++j)                                               \
                acc[i][j] = __builtin_amdgcn_mfma_f32_16x16x32_bf16(af[i], bfr[j], acc[i][j], 0, 0, 0); \
    }

    // prologue: tile0 -> slot0, tile1 -> slot1 (K-steps 0..15 of this half)
    O_STAGE(0, 0)
    O_STAGE(2048, 4096)

    for (int g = 0; g < 4; ++g) {        // i = 3g..3g+2, covers 0..11 (stages tiles 2..13)
        asm volatile("s_waitcnt vmcnt(3)" ::: "memory");
        __builtin_amdgcn_s_barrier();
        O_STAGE(4096, 8192)
        O_COMP(0, 0)
        asm volatile("s_waitcnt vmcnt(3)" ::: "memory");
        __builtin_amdgcn_s_barrier();
        O_STAGE(0, 0)
        O_COMP(2048, 4096)
        asm volatile("s_waitcnt vmcnt(3)" ::: "memory");
        __builtin_amdgcn_s_barrier();
        O_STAGE(2048, 4096)
        O_COMP(4096, 8192)
    }
    // i=12: stage tile14 -> slot2; i=13: stage tile15 -> slot0; i=14,15: drain
    asm volatile("s_waitcnt vmcnt(3)" ::: "memory");
    __builtin_amdgcn_s_barrier();
    O_STAGE(4096, 8192)
    O_COMP(0, 0)
    asm volatile("s_waitcnt vmcnt(3)" ::: "memory");
    __builtin_amdgcn_s_barrier();
    O_STAGE(0, 0)
    O_COMP(2048, 4096)
    asm volatile("s_waitcnt vmcnt(3)" ::: "memory");
    __builtin_amdgcn_s_barrier();
    O_COMP(4096, 8192)
    asm volatile("s_waitcnt vmcnt(0)" ::: "memory");
    __builtin_amdgcn_s_barrier();
    O_COMP(0, 0)

#pragma unroll
    for (int i = 0; i < 4; ++i)
#pragma unroll
        for (int j = 0; j < 2; ++j) {
            int n = n0 + wave * 32 + j * 16 + lm;
#pragma unroll
            for (int r = 0; r < 4; ++r) {
                int m = m0 + i * 16 + lq * 4 + r;
                outp[(size_t)m * EMBED + n] = acc[i][j][r];
            }
        }
#undef O_STAGE
#undef O_COMP
}

// ---------------- flash attention (R8 structure, unchanged) ----------------
__global__ __launch_bounds__(512, 4) void attn_kernel(const unsigned short* __restrict__ Qp,
                                                      const unsigned short* __restrict__ Kp,
                                                      const unsigned short* __restrict__ Vt,
                                                      unsigned short* __restrict__ att) {
    __shared__ unsigned short KV[32768];     // [0,16384): K [buf2][tile2][4096] ; [16384,32768): V
                                             // epilogue: f32 merge buffer [128][68] + l[128]
    unsigned short* Ks = KV;
    unsigned short* Vs = KV + 16384;
    const int t = threadIdx.x;               // 0..511
    const int bx = blockIdx.x;
    const int bh = bx & 31;                  // XCD-stable: same-head blocks differ by 32
    const int b = bh >> 4, h = bh & 15;
    const int q0 = (bx >> 5) * 128;
    const unsigned short* Qh = Qp + (size_t)bh * SEQ * HDIM;
    const unsigned short* Kh = Kp + (size_t)bh * SEQ * HDIM;
    const unsigned short* Vh = Vt + (size_t)bh * HDIM * SEQ;
    const int wave = t >> 6, lane = t & 63;
    const int g = wave >> 2, ws = wave & 3;  // kv-parity group / q-slice
    const int ln31 = lane & 31, halfl = lane >> 5;

    bf16x8 qf[4];
    {
        const unsigned short* qptr = Qh + (size_t)(q0 + ws * 32 + ln31) * HDIM + halfl * 8;
#pragma unroll
        for (int s = 0; s < 4; ++s) qf[s] = *(const bf16x8*)(qptr + s * 16);
    }

    // pair staging: 512 threads cover 2 tiles x 512 chunks
    const int f0 = t >> 6, m0_ = t & 31, hh0 = (t >> 5) & 1;
    const unsigned short* gK0 = Kh + (size_t)((f0 >> 2) * 32 + m0_) * HDIM + (f0 & 3) * 16 + hh0 * 8;
    const unsigned short* gV0 = Vh + (size_t)((f0 >> 2) * 32 + m0_) * SEQ + (f0 & 3) * 16 + hh0 * 8;

#define ATTN_STAGE(NBO)                                                   \
    gl_lds16(gK0,             Ks + (NBO) + wave * 512);                   \
    gl_lds16(gK0 + 64 * HDIM, Ks + (NBO) + 4096 + wave * 512);            \
    gl_lds16(gV0,             Vs + (NBO) + wave * 512);                   \
    gl_lds16(gV0 + 64,        Vs + (NBO) + 4096 + wave * 512);            \
    gK0 += 128 * HDIM; gV0 += 128;

    // prologue: pair0 -> buf0, pair1 -> buf1 (8 loads in flight); ptrs end at pair2
    ATTN_STAGE(0)
    ATTN_STAGE(8192)

    // persistent exp-offset vector: C-operand of the first QK MFMA of every chain
    f32x16 OFFS;
#pragma unroll
    for (int r = 0; r < 16; ++r) OFFS[r] = -17.312340f;   // -12*log2(e)

    f32x16 Oa[2];
#pragma unroll
    for (int mo = 0; mo < 2; ++mo)
#pragma unroll
        for (int r = 0; r < 16; ++r) Oa[mo][r] = 0.f;
    float rpA = 0.f, rpB = 0.f, rpC = 0.f, rpD = 0.f;

    for (int kt = 0; kt < 16; ++kt) {
        // wait for pair kt only: 4 newer loads (pair kt+1) stay in flight
        if (kt < 15) { asm volatile("s_waitcnt vmcnt(4)" ::: "memory"); }
        else         { asm volatile("s_waitcnt vmcnt(0)" ::: "memory"); }
        __builtin_amdgcn_s_barrier();
        const int cbo = (kt & 1) * 8192 + g * 4096;   // this group's tile of the pair

#pragma unroll
        for (int mt = 0; mt < 2; ++mt) {
            // S = K_tile . Q^T : lane holds q=ln31, kv = (r&3) + 8*(r>>2) + 4*halfl + 32*mt
            f32x16 S;
            __builtin_amdgcn_s_setprio(1);
            {
                bf16x8 af = *(const bf16x8*)&Ks[cbo + (mt * 4 + 0) * 512 + halfl * 256 + ln31 * 8];
                S = __builtin_amdgcn_mfma_f32_32x32x16_bf16(af, qf[0], OFFS, 0, 0, 0);
            }
#pragma unroll
            for (int s = 1; s < 4; ++s) {
                bf16x8 af = *(const bf16x8*)&Ks[cbo + (mt * 4 + s) * 512 + halfl * 256 + ln31 * 8];
                S = __builtin_amdgcn_mfma_f32_32x32x16_bf16(af, qf[s], S, 0, 0, 0);
            }
            __builtin_amdgcn_s_setprio(0);

            // softmax: bare v_exp_f32; partials accumulate across all tiles
#pragma unroll
            for (int rg = 0; rg < 4; ++rg) {
                float p0 = exp2_hw(S[rg * 4 + 0]);
                float p1 = exp2_hw(S[rg * 4 + 1]);
                float p2 = exp2_hw(S[rg * 4 + 2]);
                float p3 = exp2_hw(S[rg * 4 + 3]);
                S[rg * 4 + 0] = p0; rpA += p0;
                S[rg * 4 + 1] = p1; rpB += p1;
                S[rg * 4 + 2] = p2; rpC += p2;
                S[rg * 4 + 3] = p3; rpD += p3;
            }

            // PV with in-register P repack (T12)
            __builtin_amdgcn_s_setprio(1);
#pragma unroll
            for (int p = 0; p < 2; ++p) {
                unsigned int a0 = cvtpk_bf16(S[8 * p + 0], S[8 * p + 1]);
                unsigned int a1 = cvtpk_bf16(S[8 * p + 2], S[8 * p + 3]);
                unsigned int b0 = cvtpk_bf16(S[8 * p + 4], S[8 * p + 5]);
                unsigned int b1 = cvtpk_bf16(S[8 * p + 6], S[8 * p + 7]);
                pl32swap(a0, b0);
                pl32swap(a1, b1);
                union { unsigned int u[4]; bf16x8 v; } bp;
                bp.u[0] = a0; bp.u[1] = a1; bp.u[2] = b0; bp.u[3] = b1;
                const int sp = mt * 2 + p;
#pragma unroll
                for (int mo = 0; mo < 2; ++mo) {
                    bf16x8 av = *(const bf16x8*)&Vs[cbo + (mo * 4 + sp) * 512 + halfl * 256 + ln31 * 8];
                    Oa[mo] = __builtin_amdgcn_mfma_f32_32x32x16_bf16(av, bp.v, Oa[mo], 0, 0, 0);
                }
            }
            __builtin_amdgcn_s_setprio(0);
        }

        if (kt < 14) {
            __builtin_amdgcn_s_barrier();   // all waves done reading buf cur
            const int nbo = (kt & 1) * 8192;
            ATTN_STAGE(nbo)                 // pair kt+2 -> buf cur; stays in flight
        }
    }
#undef ATTN_STAGE

    // per-q sum over this group's kv range (lane halves cover disjoint kv rows)
    float lsum = (rpA + rpB) + (rpC + rpD);
    unsigned int la = __float_as_uint(lsum), lb = __float_as_uint(lsum);
    pl32swap(la, lb);
    float ltot = __uint_as_float(la) + __uint_as_float(lb);

    // in-LDS merge of the two kv-parity groups (f32, exact)
    __syncthreads();                        // all K/V ds_reads complete; LDS reusable
    float* shO = (float*)KV;                // [128][68] padded (stride 68 -> 4-way banks)
    float* shL = (float*)KV + 128 * 68;
    const int qr = ws * 32 + ln31;
    if (g == 1) {
#pragma unroll
        for (int mo = 0; mo < 2; ++mo)
#pragma unroll
            for (int rg = 0; rg < 4; ++rg) {
                float4 v;
                v.x = Oa[mo][rg * 4 + 0]; v.y = Oa[mo][rg * 4 + 1];
                v.z = Oa[mo][rg * 4 + 2]; v.w = Oa[mo][rg * 4 + 3];
                *(float4*)&shO[qr * 68 + mo * 32 + rg * 8 + halfl * 4] = v;
            }
        shL[qr] = ltot;
    }
    __syncthreads();
    if (g == 0) {
        float inv = 1.f / (ltot + shL[qr]);
        unsigned short* orow = att + (size_t)(b * SEQ + q0 + qr) * EMBED + h * HDIM;
#pragma unroll
        for (int mo = 0; mo < 2; ++mo)
#pragma unroll
            for (int rg = 0; rg < 4; ++rg) {
                float4 v = *(const float4*)&shO[qr * 68 + mo * 32 + rg * 8 + halfl * 4];
                u16x4 ow = {f2bf((Oa[mo][rg * 4 + 0] + v.x) * inv),
                            f2bf((Oa[mo][rg * 4 + 1] + v.y) * inv),
                            f2bf((Oa[mo][rg * 4 + 2] + v.z) * inv),
                            f2bf((Oa[mo][rg * 4 + 3] + v.w) * inv)};
                *(u16x4*)&orow[mo * 32 + rg * 8 + halfl * 4] = ow;
            }
    }
}

// ---------------- row LayerNorm: x = x0 + x1 + bias + residual, then normalize ----------------
__global__ __launch_bounds__(256) void ln_kernel(const float* __restrict__ x0,
                                                 const float* __restrict__ x1,
                                                 const float* __restrict__ residual,
                                                 const float* __restrict__ bo,
                                                 const float* __restrict__ gamma,
                                                 const float* __restrict__ beta,
                                                 float* __restrict__ out) {
    __shared__ float red[8];
    const int row = blockIdx.x, t = threadIdx.x;
    size_t base = (size_t)row * EMBED + t * 4;
    float4 a = *(const float4*)(x0 + base);
    float4 c = *(const float4*)(x1 + base);
    float4 r = *(const float4*)(residual + base);
    float4 bb0 = *(const float4*)(bo + t * 4);
    float4 v;
    v.x = a.x + c.x + bb0.x + r.x;
    v.y = a.y + c.y + bb0.y + r.y;
    v.z = a.z + c.z + bb0.z + r.z;
    v.w = a.w + c.w + bb0.w + r.w;
    float s = v.x + v.y + v.z + v.w;
    float ss = v.x * v.x + v.y * v.y + v.z * v.z + v.w * v.w;
#pragma unroll
    for (int o = 1; o < 64; o <<= 1) {
        s += __shfl_xor(s, o);
        ss += __shfl_xor(ss, o);
    }
    int wave = t >> 6, lane = t & 63;
    if (lane == 0) { red[wave] = s; red[4 + wave] = ss; }
    __syncthreads();
    s = red[0] + red[1] + red[2] + red[3];
    ss = red[4] + red[5] + red[6] + red[7];
    float mu = s * (1.f / EMBED);
    float var = ss * (1.f / EMBED) - mu * mu;
    float rstd = rsqrtf(var + 1e-5f);
    float4 g = *(const float4*)(gamma + t * 4);
    float4 bb = *(const float4*)(beta + t * 4);
    float4 o;
    o.x = (v.x - mu) * rstd * g.x + bb.x;
    o.y = (v.y - mu) * rstd * g.y + bb.y;
    o.z = (v.z - mu) * rstd * g.z + bb.z;
    o.w = (v.w - mu) * rstd * g.w + bb.w;
    *(float4*)(out + (size_t)row * EMBED + t * 4) = o;
}

// ---------------- launch ----------------
extern "C" void kernel_launch(void* const* d_in, const int* in_sizes, int n_in,
                              void* d_out, int out_size, void* d_ws, size_t ws_size,
                              hipStream_t stream) {
    const float* query = (const float*)d_in[0];
    const float* key_  = (const float*)d_in[1];
    const float* value = (const float*)d_in[2];
    const float* Wq = (const float*)d_in[3];
    const float* bq = (const float*)d_in[4];
    const float* Wk = (const float*)d_in[5];
    const float* bk = (const float*)d_in[6];
    const float* Wv = (const float*)d_in[7];
    const float* bv = (const float*)d_in[8];
    const float* Wo = (const float*)d_in[9];
    const float* bo = (const float*)d_in[10];
    const float* gamma = (const float*)d_in[11];
    const float* beta  = (const float*)d_in[12];

    char* ws = (char*)d_ws;
    const size_t MB = 1024 * 1024;
    unsigned short* qb  = (unsigned short*)(ws + 0);
    unsigned short* kb  = (unsigned short*)(ws + 8 * MB);
    unsigned short* vb  = (unsigned short*)(ws + 16 * MB);
    unsigned short* Wqt = (unsigned short*)(ws + 24 * MB);
    unsigned short* Wkt = (unsigned short*)(ws + 26 * MB);
    unsigned short* Wvt = (unsigned short*)(ws + 28 * MB);
    unsigned short* Wot = (unsigned short*)(ws + 30 * MB);
    unsigned short* Qp  = (unsigned short*)(ws + 32 * MB);
    unsigned short* Kp  = (unsigned short*)(ws + 40 * MB);
    unsigned short* Vtb = (unsigned short*)(ws + 48 * MB);
    unsigned short* att = (unsigned short*)(ws + 0);        // aliases qb (dead after Q-proj)
    float*          xbuf0 = (float*)(ws + 8 * MB);          // aliases kb+vb (dead after K/V-proj)
    float*          xbuf1 = (float*)(ws + 32 * MB);         // aliases Qp+Kp (dead after attn) — 56MB footprint

    cvt3_kernel<<<dim3(2048, 3), 256, 0, stream>>>(query, key_, value, qb, kb, vb);
    transpose4_kernel<<<dim3(32, 32, 4), dim3(32, 8), 0, stream>>>(Wq, Wk, Wv, Wo, Wqt, Wkt, Wvt, Wot);

    gemm_qkv_kernel<<<dim3(32, 8, 3), 256, 0, stream>>>(qb, kb, vb, Wqt, Wkt, Wvt,
                                                        bq, bk, bv, Qp, Kp, Vtb);

    attn_kernel<<<dim3(512), 512, 0, stream>>>(Qp, Kp, Vtb, att);

    gemm_o_kernel<<<dim3(64, 8, 2), 256, 0, stream>>>(att, Wot, xbuf0, xbuf1);
    ln_kernel<<<ROWS, 256, 0, stream>>>(xbuf0, xbuf1, query, bo, gamma, beta, (float*)d_out);
}

// Round 11
// 223.918 us; speedup vs baseline: 1.0152x; 1.0152x over previous
//
#include <hip/hip_runtime.h>

// ---------------- problem constants ----------------
#define EMBED 1024
#define NHEAD 16
#define HDIM  64
#define BATCH 2
#define SEQ   2048
#define ROWS  (BATCH*SEQ)   // 4096

typedef __bf16 bf16x8 __attribute__((ext_vector_type(8)));
typedef float  f32x4  __attribute__((ext_vector_type(4)));
typedef float  f32x16 __attribute__((ext_vector_type(16)));
typedef unsigned short u16x8 __attribute__((ext_vector_type(8)));
typedef unsigned short u16x4 __attribute__((ext_vector_type(4)));

__device__ __forceinline__ unsigned short f2bf(float f) {
    unsigned int u = __float_as_uint(f);
    u += 0x7FFFu + ((u >> 16) & 1u);          // round-to-nearest-even
    return (unsigned short)(u >> 16);
}
__device__ __forceinline__ f32x4 zero4() { f32x4 z = {0.f, 0.f, 0.f, 0.f}; return z; }

// pack two f32 -> bf16 pair in one instruction (RNE)
__device__ __forceinline__ unsigned int cvtpk_bf16(float lo, float hi) {
    unsigned int r;
    asm("v_cvt_pk_bf16_f32 %0, %1, %2" : "=v"(r) : "v"(lo), "v"(hi));
    return r;
}
// new_a = [a.row0 | b.row0], new_b = [a.row1 | b.row1]  (rows = lane<32 / lane>=32)
__device__ __forceinline__ void pl32swap(unsigned int &a, unsigned int &b) {
    asm("v_permlane32_swap_b32 %0, %1" : "+v"(a), "+v"(b));
}
// hardware exp2 (v_exp_f32: D = 2^S0)
__device__ __forceinline__ float exp2_hw(float x) {
    float r;
    asm("v_exp_f32 %0, %1" : "=v"(r) : "v"(x));
    return r;
}

// async global->LDS, 16B per lane; lds dest is wave-uniform base (+lane*16 by HW)
__device__ __forceinline__ void gl_lds16(const unsigned short* g, unsigned short* l) {
    __builtin_amdgcn_global_load_lds(
        (const __attribute__((address_space(1))) void*)g,
        (__attribute__((address_space(3))) void*)l, 16, 0, 0);
}

// ---------------- fused prep: f32->bf16 cast (q/k/v) + 4x weight transpose ------------
// R11: one launch instead of two — cvt blocks (bx<6144) and transpose blocks (bx>=6144)
// co-schedule across CUs, so prep time ~ max(cvt, transpose) instead of sum + gap.
__global__ __launch_bounds__(256) void prep_kernel(
    const float* __restrict__ q, const float* __restrict__ k, const float* __restrict__ v,
    unsigned short* __restrict__ qo, unsigned short* __restrict__ ko,
    unsigned short* __restrict__ vo,
    const float* __restrict__ w0, const float* __restrict__ w1,
    const float* __restrict__ w2, const float* __restrict__ w3,
    unsigned short* __restrict__ o0, unsigned short* __restrict__ o1,
    unsigned short* __restrict__ o2, unsigned short* __restrict__ o3) {
    __shared__ float tile[32][33];
    const int bx = blockIdx.x, t = threadIdx.x;
    if (bx < 6144) {
        // cast: 8 f32 -> 8 bf16 per thread, 16B stores
        const float* in; unsigned short* out;
        int m = bx >> 11;                    // matrix 0..2
        int blk = bx & 2047;
        if (m == 0)      { in = q; out = qo; }
        else if (m == 1) { in = k; out = ko; }
        else             { in = v; out = vo; }
        int i = (blk * 256 + t) * 8;
        float4 a = *(const float4*)(in + i);
        float4 b = *(const float4*)(in + i + 4);
        u16x8 o = {f2bf(a.x), f2bf(a.y), f2bf(a.z), f2bf(a.w),
                   f2bf(b.x), f2bf(b.y), f2bf(b.z), f2bf(b.w)};
        *(u16x8*)(out + i) = o;
    } else {
        // W [K,N] f32 -> Wt [N,K] bf16, 32x32 tiles
        int idx = bx - 6144;
        int z = idx >> 10;                   // matrix 0..3
        int rem = idx & 1023;
        int bxx = rem & 31, byy = rem >> 5;
        const float* in; unsigned short* out;
        if (z == 0)      { in = w0; out = o0; }
        else if (z == 1) { in = w1; out = o1; }
        else if (z == 2) { in = w2; out = o2; }
        else             { in = w3; out = o3; }
        int tx = t & 31, ty = t >> 5;        // 32 x 8
        int x = bxx * 32 + tx;
        int y0 = byy * 32 + ty;
#pragma unroll
        for (int r = 0; r < 4; ++r)
            tile[ty + 8 * r][tx] = in[(size_t)(y0 + 8 * r) * EMBED + x];
        __syncthreads();
        int ox = byy * 32 + tx;
        int oy = bxx * 32 + ty;
#pragma unroll
        for (int r = 0; r < 4; ++r)
            out[(size_t)(oy + 8 * r) * EMBED + ox] = f2bf(tile[tx][ty + 8 * r]);
    }
}

// ---------------- 128x128 bf16 GEMM, ring-3 single-barrier K-loop (T3/T4) ------
__global__ __launch_bounds__(256, 2) void gemm_qkv_kernel(
    const unsigned short* __restrict__ qb, const unsigned short* __restrict__ kb,
    const unsigned short* __restrict__ vb,
    const unsigned short* __restrict__ Wqt, const unsigned short* __restrict__ Wkt,
    const unsigned short* __restrict__ Wvt,
    const float* __restrict__ bq, const float* __restrict__ bk, const float* __restrict__ bv,
    unsigned short* __restrict__ Qp, unsigned short* __restrict__ Kp,
    unsigned short* __restrict__ Vtb) {
    __shared__ unsigned short smem[24576];   // A slots [0,12288) x3, B slots [12288,24576) x3
                                             // epilogue: reused as 64x136 transpose tile
    const unsigned short *A, *Bt; const float* bias; unsigned short* outp; int mode; float osc;
    if (blockIdx.z == 0)      { A = qb; Bt = Wqt; bias = bq; outp = Qp;  mode = 0; osc = 0.18033688f; }
    else if (blockIdx.z == 1) { A = kb; Bt = Wkt; bias = bk; outp = Kp;  mode = 0; osc = 1.0f; }
    else                      { A = vb; Bt = Wvt; bias = bv; outp = Vtb; mode = 1; osc = 1.0f; }

    const int t = threadIdx.x;
    const int m0 = blockIdx.x * 128, n0 = blockIdx.y * 128;
    const int wave = t >> 6, lane = t & 63;
    const int wr = wave >> 1, wc = wave & 1;             // 2x2 wave grid, 64x64 each
    const int lm = lane & 15, lq = lane >> 4;
    const int sr = t >> 2;                               // staging row 0..63
    const int csrc = (t & 3) ^ ((sr >> 1) & 3);          // chunk-XOR swizzle source
    const int pa = lq ^ ((lm >> 1) & 3);                 // fragment chunk position

    const unsigned short* gA = A + (size_t)(m0 + sr) * EMBED + csrc * 8;
    const unsigned short* gB = Bt + (size_t)(n0 + sr) * EMBED + csrc * 8;

    f32x4 acc[4][4];
#pragma unroll
    for (int i = 0; i < 4; ++i)
#pragma unroll
        for (int j = 0; j < 4; ++j) acc[i][j] = zero4();

#define QKV_STAGE(SOFF)                                                      \
    gl_lds16(gA,              smem + (SOFF) + wave * 512);                   \
    gl_lds16(gA + 64 * EMBED, smem + (SOFF) + 2048 + wave * 512);            \
    gl_lds16(gB,              smem + 12288 + (SOFF) + wave * 512);           \
    gl_lds16(gB + 64 * EMBED, smem + 12288 + (SOFF) + 2048 + wave * 512);    \
    gA += 32; gB += 32;

#define QKV_COMP(COFF)                                                                 \
    {                                                                                  \
        bf16x8 af[4], bfr[4];                                                          \
        _Pragma("unroll")                                                              \
        for (int i = 0; i < 4; ++i)                                                    \
            af[i] = *(const bf16x8*)&smem[(COFF) + (wr * 64 + i * 16 + lm) * 32 + pa * 8]; \
        _Pragma("unroll")                                                              \
        for (int j = 0; j < 4; ++j)                                                    \
            bfr[j] = *(const bf16x8*)&smem[12288 + (COFF) + (wc * 64 + j * 16 + lm) * 32 + pa * 8]; \
        _Pragma("unroll")                                                              \
        for (int i = 0; i < 4; ++i)                                                    \
            _Pragma("unroll")                                                          \
            for (int j = 0; j < 4; ++j)                                                \
                acc[i][j] = __builtin_amdgcn_mfma_f32_16x16x32_bf16(af[i], bfr[j], acc[i][j], 0, 0, 0); \
    }

    // prologue: tile0 -> slot0, tile1 -> slot1; ptrs end at tile2
    QKV_STAGE(0)
    QKV_STAGE(4096)

    for (int g = 0; g < 10; ++g) {       // i = 3g, 3g+1, 3g+2  (covers 0..29)
        asm volatile("s_waitcnt vmcnt(4)" ::: "memory");
        __builtin_amdgcn_s_barrier();
        QKV_STAGE(8192)                  // tile i+2 -> slot2
        QKV_COMP(0)
        asm volatile("s_waitcnt vmcnt(4)" ::: "memory");
        __builtin_amdgcn_s_barrier();
        QKV_STAGE(0)                     // -> slot0
        QKV_COMP(4096)
        asm volatile("s_waitcnt vmcnt(4)" ::: "memory");
        __builtin_amdgcn_s_barrier();
        QKV_STAGE(4096)                  // -> slot1
        QKV_COMP(8192)
    }
    // i=30 (slot0, no stage), i=31 (slot1, drain)
    asm volatile("s_waitcnt vmcnt(4)" ::: "memory");
    __builtin_amdgcn_s_barrier();
    QKV_COMP(0)
    asm volatile("s_waitcnt vmcnt(0)" ::: "memory");
    __builtin_amdgcn_s_barrier();
    QKV_COMP(4096)

    const int row = t >> 2, seg = t & 3;     // readback: 64B per thread, coalesced
    if (mode == 0) {
        // out[s][hd]: two passes over m-halves; LDS tile Ct[ml 64][nl 128] (+8 pad)
#pragma unroll
        for (int p = 0; p < 2; ++p) {
            __syncthreads();
            if (wr == p) {
#pragma unroll
                for (int i = 0; i < 4; ++i)
#pragma unroll
                    for (int j = 0; j < 4; ++j) {
                        float bn = bias[n0 + wc * 64 + j * 16 + lm];
                        int nl = wc * 64 + j * 16 + lm;
#pragma unroll
                        for (int r = 0; r < 4; ++r)
                            smem[(i * 16 + lq * 4 + r) * 136 + nl] =
                                f2bf((acc[i][j][r] + bn) * osc);
                    }
            }
            __syncthreads();
            int m = m0 + p * 64 + row;
            int b = m >> 11, sI = m & 2047;
            int ncol = n0 + seg * 32;
            int h = ncol >> 6, hd0 = ncol & 63;
            unsigned short* dst = outp + (((size_t)((b * NHEAD + h) * SEQ + sI)) << 6) + hd0;
            const unsigned short* src = smem + row * 136 + seg * 32;
            *(u16x8*)(dst)      = *(const u16x8*)(src);
            *(u16x8*)(dst + 8)  = *(const u16x8*)(src + 8);
            *(u16x8*)(dst + 16) = *(const u16x8*)(src + 16);
            *(u16x8*)(dst + 24) = *(const u16x8*)(src + 24);
        }
    } else {
        // out[hd][s]: two passes over n-halves; LDS tile Cn[nl 64][ml 128] (+8 pad), packed writes
#pragma unroll
        for (int p = 0; p < 2; ++p) {
            __syncthreads();
            if (wc == p) {
#pragma unroll
                for (int i = 0; i < 4; ++i)
#pragma unroll
                    for (int j = 0; j < 4; ++j) {
                        float bn = bias[n0 + p * 64 + j * 16 + lm];
                        u16x4 pw = {f2bf(acc[i][j][0] + bn), f2bf(acc[i][j][1] + bn),
                                    f2bf(acc[i][j][2] + bn), f2bf(acc[i][j][3] + bn)};
                        *(u16x4*)&smem[(j * 16 + lm) * 136 + wr * 64 + i * 16 + lq * 4] = pw;
                    }
            }
            __syncthreads();
            int n = n0 + p * 64 + row;
            int h = n >> 6, hd = n & 63;
            int b = m0 >> 11;
            int s0 = (m0 & 2047) + seg * 32;
            unsigned short* dst = outp + ((size_t)((b * NHEAD + h) * HDIM + hd)) * SEQ + s0;
            const unsigned short* src = smem + row * 136 + seg * 32;
            *(u16x8*)(dst)      = *(const u16x8*)(src);
            *(u16x8*)(dst + 8)  = *(const u16x8*)(src + 8);
            *(u16x8*)(dst + 16) = *(const u16x8*)(src + 16);
            *(u16x8*)(dst + 24) = *(const u16x8*)(src + 24);
        }
    }
#undef QKV_STAGE
#undef QKV_COMP
}

// ---------------- O-projection GEMM: M64 x N128 tiles, ring-3 single-barrier (R8 form) ----
__global__ __launch_bounds__(256, 2) void gemm_o_kernel(
    const unsigned short* __restrict__ att, const unsigned short* __restrict__ Wot,
    const float* __restrict__ bo, float* __restrict__ xbuf,
    const float* __restrict__ residual) {
    __shared__ unsigned short smem[18432];   // A slots [0,6144) x3 (2048 each), B slots [6144,18432) x3 (4096 each)
    const int t = threadIdx.x;
    const int m0 = blockIdx.x * 64, n0 = blockIdx.y * 128;
    const int wave = t >> 6, lane = t & 63;
    const int lm = lane & 15, lq = lane >> 4;
    const int sr = t >> 2;
    const int csrc = (t & 3) ^ ((sr >> 1) & 3);
    const int pa = lq ^ ((lm >> 1) & 3);

    const unsigned short* gA = att + (size_t)(m0 + sr) * EMBED + csrc * 8;
    const unsigned short* gB = Wot + (size_t)(n0 + sr) * EMBED + csrc * 8;

    f32x4 acc[4][2];
#pragma unroll
    for (int i = 0; i < 4; ++i)
#pragma unroll
        for (int j = 0; j < 2; ++j) acc[i][j] = zero4();

#define O_STAGE(SA, SB)                                                  \
    gl_lds16(gA,              smem + (SA) + wave * 512);                 \
    gl_lds16(gB,              smem + 6144 + (SB) + wave * 512);          \
    gl_lds16(gB + 64 * EMBED, smem + 6144 + (SB) + 2048 + wave * 512);   \
    gA += 32; gB += 32;

#define O_COMP(SA, SB)                                                                \
    {                                                                                 \
        bf16x8 af[4], bfr[2];                                                         \
        _Pragma("unroll")                                                             \
        for (int i = 0; i < 4; ++i)                                                   \
            af[i] = *(const bf16x8*)&smem[(SA) + (i * 16 + lm) * 32 + pa * 8];        \
        _Pragma("unroll")                                                             \
        for (int j = 0; j < 2; ++j)                                                   \
            bfr[j] = *(const bf16x8*)&smem[6144 + (SB) + (wave * 32 + j * 16 + lm) * 32 + pa * 8]; \
        _Pragma("unroll")                                                             \
        for (int i = 0; i < 4; ++i)                                                   \
            _Pragma("unroll")                                                         \
            for (int j = 0; j < 2; ++j)                                               \
                acc[i][j] = __builtin_amdgcn_mfma_f32_16x16x32_bf16(af[i], bfr[j], acc[i][j], 0, 0, 0); \
    }

    // prologue: tile0 -> slot0, tile1 -> slot1
    O_STAGE(0, 0)
    O_STAGE(2048, 4096)

    for (int g = 0; g < 10; ++g) {
        asm volatile("s_waitcnt vmcnt(3)" ::: "memory");
        __builtin_amdgcn_s_barrier();
        O_STAGE(4096, 8192)
        O_COMP(0, 0)
        asm volatile("s_waitcnt vmcnt(3)" ::: "memory");
        __builtin_amdgcn_s_barrier();
        O_STAGE(0, 0)
        O_COMP(2048, 4096)
        asm volatile("s_waitcnt vmcnt(3)" ::: "memory");
        __builtin_amdgcn_s_barrier();
        O_STAGE(2048, 4096)
        O_COMP(4096, 8192)
    }
    asm volatile("s_waitcnt vmcnt(3)" ::: "memory");
    __builtin_amdgcn_s_barrier();
    O_COMP(0, 0)
    asm volatile("s_waitcnt vmcnt(0)" ::: "memory");
    __builtin_amdgcn_s_barrier();
    O_COMP(2048, 4096)

#pragma unroll
    for (int i = 0; i < 4; ++i)
#pragma unroll
        for (int j = 0; j < 2; ++j) {
            int n = n0 + wave * 32 + j * 16 + lm;
            float bn = bo[n];
#pragma unroll
            for (int r = 0; r < 4; ++r) {
                int m = m0 + i * 16 + lq * 4 + r;
                size_t idx = (size_t)m * EMBED + n;
                xbuf[idx] = acc[i][j][r] + bn + residual[idx];
            }
        }
#undef O_STAGE
#undef O_COMP
}

// ---------------- flash attention ----------------
// R11: QK-both-mt-first restructure. R8/R10 serialized QK(mt)->SM(mt)->PV(mt) per mt,
// putting the full S->exp->repack->PV dependency chain on the critical path twice per
// pair. Now: QK(S0), QK(S1) upfront (2 independent 4-MFMA chains), then SM+PV(S0),
// SM+PV(S1) — softmax(S1) VALU/trans is independent of PV(S0) MFMA in one basic block,
// so the two pipes overlap (T15 mechanism via code motion). +16 VGPR for the second
// live S; still >=4 waves/SIMD. Counted-vmcnt pair pipeline + XCD mapping unchanged.
__global__ __launch_bounds__(512, 4) void attn_kernel(const unsigned short* __restrict__ Qp,
                                                      const unsigned short* __restrict__ Kp,
                                                      const unsigned short* __restrict__ Vt,
                                                      unsigned short* __restrict__ att) {
    __shared__ unsigned short KV[32768];     // [0,16384): K [buf2][tile2][4096] ; [16384,32768): V
                                             // epilogue: f32 merge buffer [128][68] + l[128]
    unsigned short* Ks = KV;
    unsigned short* Vs = KV + 16384;
    const int t = threadIdx.x;               // 0..511
    const int bx = blockIdx.x;
    const int bh = bx & 31;                  // XCD-stable: same-head blocks differ by 32
    const int b = bh >> 4, h = bh & 15;
    const int q0 = (bx >> 5) * 128;
    const unsigned short* Qh = Qp + (size_t)bh * SEQ * HDIM;
    const unsigned short* Kh = Kp + (size_t)bh * SEQ * HDIM;
    const unsigned short* Vh = Vt + (size_t)bh * HDIM * SEQ;
    const int wave = t >> 6, lane = t & 63;
    const int g = wave >> 2, ws = wave & 3;  // kv-parity group / q-slice
    const int ln31 = lane & 31, halfl = lane >> 5;

    bf16x8 qf[4];
    {
        const unsigned short* qptr = Qh + (size_t)(q0 + ws * 32 + ln31) * HDIM + halfl * 8;
#pragma unroll
        for (int s = 0; s < 4; ++s) qf[s] = *(const bf16x8*)(qptr + s * 16);
    }

    // pair staging: 512 threads cover 2 tiles x 512 chunks
    const int f0 = t >> 6, m0_ = t & 31, hh0 = (t >> 5) & 1;
    const unsigned short* gK0 = Kh + (size_t)((f0 >> 2) * 32 + m0_) * HDIM + (f0 & 3) * 16 + hh0 * 8;
    const unsigned short* gV0 = Vh + (size_t)((f0 >> 2) * 32 + m0_) * SEQ + (f0 & 3) * 16 + hh0 * 8;

#define ATTN_STAGE(NBO)                                                   \
    gl_lds16(gK0,             Ks + (NBO) + wave * 512);                   \
    gl_lds16(gK0 + 64 * HDIM, Ks + (NBO) + 4096 + wave * 512);            \
    gl_lds16(gV0,             Vs + (NBO) + wave * 512);                   \
    gl_lds16(gV0 + 64,        Vs + (NBO) + 4096 + wave * 512);            \
    gK0 += 128 * HDIM; gV0 += 128;

    // prologue: pair0 -> buf0, pair1 -> buf1 (8 loads in flight); ptrs end at pair2
    ATTN_STAGE(0)
    ATTN_STAGE(8192)

    // persistent exp-offset vector: C-operand of the first QK MFMA of every chain
    f32x16 OFFS;
#pragma unroll
    for (int r = 0; r < 16; ++r) OFFS[r] = -17.312340f;   // -12*log2(e)

    f32x16 Oa[2];
#pragma unroll
    for (int mo = 0; mo < 2; ++mo)
#pragma unroll
        for (int r = 0; r < 16; ++r) Oa[mo][r] = 0.f;
    float rpA = 0.f, rpB = 0.f, rpC = 0.f, rpD = 0.f;

    for (int kt = 0; kt < 16; ++kt) {
        // wait for pair kt only: 4 newer loads (pair kt+1) stay in flight
        if (kt < 15) { asm volatile("s_waitcnt vmcnt(4)" ::: "memory"); }
        else         { asm volatile("s_waitcnt vmcnt(0)" ::: "memory"); }
        __builtin_amdgcn_s_barrier();
        const int cbo = (kt & 1) * 8192 + g * 4096;   // this group's tile of the pair

        // QK for BOTH mt halves first: lane holds q=ln31,
        // kv = (r&3) + 8*(r>>2) + 4*halfl + 32*mt
        f32x16 S0, S1;
        __builtin_amdgcn_s_setprio(1);
        {
            bf16x8 af = *(const bf16x8*)&Ks[cbo + halfl * 256 + ln31 * 8];
            S0 = __builtin_amdgcn_mfma_f32_32x32x16_bf16(af, qf[0], OFFS, 0, 0, 0);
        }
#pragma unroll
        for (int s = 1; s < 4; ++s) {
            bf16x8 af = *(const bf16x8*)&Ks[cbo + s * 512 + halfl * 256 + ln31 * 8];
            S0 = __builtin_amdgcn_mfma_f32_32x32x16_bf16(af, qf[s], S0, 0, 0, 0);
        }
        {
            bf16x8 af = *(const bf16x8*)&Ks[cbo + 4 * 512 + halfl * 256 + ln31 * 8];
            S1 = __builtin_amdgcn_mfma_f32_32x32x16_bf16(af, qf[0], OFFS, 0, 0, 0);
        }
#pragma unroll
        for (int s = 1; s < 4; ++s) {
            bf16x8 af = *(const bf16x8*)&Ks[cbo + (4 + s) * 512 + halfl * 256 + ln31 * 8];
            S1 = __builtin_amdgcn_mfma_f32_32x32x16_bf16(af, qf[s], S1, 0, 0, 0);
        }
        __builtin_amdgcn_s_setprio(0);

        // SM+PV per mt; SM(S1) is independent of PV(S0) -> dual-pipe overlap
#define SMPV(S, MT)                                                               \
        {                                                                         \
            _Pragma("unroll")                                                     \
            for (int rg = 0; rg < 4; ++rg) {                                      \
                float p0 = exp2_hw(S[rg * 4 + 0]);                                \
                float p1 = exp2_hw(S[rg * 4 + 1]);                                \
                float p2 = exp2_hw(S[rg * 4 + 2]);                                \
                float p3 = exp2_hw(S[rg * 4 + 3]);                                \
                S[rg * 4 + 0] = p0; rpA += p0;                                    \
                S[rg * 4 + 1] = p1; rpB += p1;                                    \
                S[rg * 4 + 2] = p2; rpC += p2;                                    \
                S[rg * 4 + 3] = p3; rpD += p3;                                    \
            }                                                                     \
            __builtin_amdgcn_s_setprio(1);                                        \
            _Pragma("unroll")                                                     \
            for (int p = 0; p < 2; ++p) {                                         \
                unsigned int a0 = cvtpk_bf16(S[8 * p + 0], S[8 * p + 1]);         \
                unsigned int a1 = cvtpk_bf16(S[8 * p + 2], S[8 * p + 3]);         \
                unsigned int b0 = cvtpk_bf16(S[8 * p + 4], S[8 * p + 5]);         \
                unsigned int b1 = cvtpk_bf16(S[8 * p + 6], S[8 * p + 7]);         \
                pl32swap(a0, b0);                                                 \
                pl32swap(a1, b1);                                                 \
                union { unsigned int u[4]; bf16x8 v; } bp;                        \
                bp.u[0] = a0; bp.u[1] = a1; bp.u[2] = b0; bp.u[3] = b1;           \
                const int sp = (MT) * 2 + p;                                      \
                _Pragma("unroll")                                                 \
                for (int mo = 0; mo < 2; ++mo) {                                  \
                    bf16x8 av = *(const bf16x8*)&Vs[cbo + (mo * 4 + sp) * 512 + halfl * 256 + ln31 * 8]; \
                    Oa[mo] = __builtin_amdgcn_mfma_f32_32x32x16_bf16(av, bp.v, Oa[mo], 0, 0, 0); \
                }                                                                 \
            }                                                                     \
            __builtin_amdgcn_s_setprio(0);                                        \
        }

        SMPV(S0, 0)
        SMPV(S1, 1)
#undef SMPV

        if (kt < 14) {
            __builtin_amdgcn_s_barrier();   // all waves done reading buf cur
            const int nbo = (kt & 1) * 8192;
            ATTN_STAGE(nbo)                 // pair kt+2 -> buf cur; stays in flight
        }
    }
#undef ATTN_STAGE

    // per-q sum over this group's kv range (lane halves cover disjoint kv rows)
    float lsum = (rpA + rpB) + (rpC + rpD);
    unsigned int la = __float_as_uint(lsum), lb = __float_as_uint(lsum);
    pl32swap(la, lb);
    float ltot = __uint_as_float(la) + __uint_as_float(lb);

    // in-LDS merge of the two kv-parity groups (f32, exact)
    __syncthreads();                        // all K/V ds_reads complete; LDS reusable
    float* shO = (float*)KV;                // [128][68] padded
    float* shL = (float*)KV + 128 * 68;
    const int qr = ws * 32 + ln31;
    if (g == 1) {
#pragma unroll
        for (int mo = 0; mo < 2; ++mo)
#pragma unroll
            for (int rg = 0; rg < 4; ++rg) {
                float4 v;
                v.x = Oa[mo][rg * 4 + 0]; v.y = Oa[mo][rg * 4 + 1];
                v.z = Oa[mo][rg * 4 + 2]; v.w = Oa[mo][rg * 4 + 3];
                *(float4*)&shO[qr * 68 + mo * 32 + rg * 8 + halfl * 4] = v;
            }
        shL[qr] = ltot;
    }
    __syncthreads();
    if (g == 0) {
        float inv = 1.f / (ltot + shL[qr]);
        unsigned short* orow = att + (size_t)(b * SEQ + q0 + qr) * EMBED + h * HDIM;
#pragma unroll
        for (int mo = 0; mo < 2; ++mo)
#pragma unroll
            for (int rg = 0; rg < 4; ++rg) {
                float4 v = *(const float4*)&shO[qr * 68 + mo * 32 + rg * 8 + halfl * 4];
                u16x4 ow = {f2bf((Oa[mo][rg * 4 + 0] + v.x) * inv),
                            f2bf((Oa[mo][rg * 4 + 1] + v.y) * inv),
                            f2bf((Oa[mo][rg * 4 + 2] + v.z) * inv),
                            f2bf((Oa[mo][rg * 4 + 3] + v.w) * inv)};
                *(u16x4*)&orow[mo * 32 + rg * 8 + halfl * 4] = ow;
            }
    }
}

// ---------------- row LayerNorm (one block per row, R8 form) ----------------
__global__ __launch_bounds__(256) void ln_kernel(const float* __restrict__ x,
                                                 const float* __restrict__ gamma,
                                                 const float* __restrict__ beta,
                                                 float* __restrict__ out) {
    __shared__ float red[8];
    const int row = blockIdx.x, t = threadIdx.x;
    float4 v = *(const float4*)(x + (size_t)row * EMBED + t * 4);
    float s = v.x + v.y + v.z + v.w;
    float ss = v.x * v.x + v.y * v.y + v.z * v.z + v.w * v.w;
#pragma unroll
    for (int o = 1; o < 64; o <<= 1) {
        s += __shfl_xor(s, o);
        ss += __shfl_xor(ss, o);
    }
    int wave = t >> 6, lane = t & 63;
    if (lane == 0) { red[wave] = s; red[4 + wave] = ss; }
    __syncthreads();
    s = red[0] + red[1] + red[2] + red[3];
    ss = red[4] + red[5] + red[6] + red[7];
    float mu = s * (1.f / EMBED);
    float var = ss * (1.f / EMBED) - mu * mu;
    float rstd = rsqrtf(var + 1e-5f);
    float4 g = *(const float4*)(gamma + t * 4);
    float4 bb = *(const float4*)(beta + t * 4);
    float4 o;
    o.x = (v.x - mu) * rstd * g.x + bb.x;
    o.y = (v.y - mu) * rstd * g.y + bb.y;
    o.z = (v.z - mu) * rstd * g.z + bb.z;
    o.w = (v.w - mu) * rstd * g.w + bb.w;
    *(float4*)(out + (size_t)row * EMBED + t * 4) = o;
}

// ---------------- launch ----------------
extern "C" void kernel_launch(void* const* d_in, const int* in_sizes, int n_in,
                              void* d_out, int out_size, void* d_ws, size_t ws_size,
                              hipStream_t stream) {
    const float* query = (const float*)d_in[0];
    const float* key_  = (const float*)d_in[1];
    const float* value = (const float*)d_in[2];
    const float* Wq = (const float*)d_in[3];
    const float* bq = (const float*)d_in[4];
    const float* Wk = (const float*)d_in[5];
    const float* bk = (const float*)d_in[6];
    const float* Wv = (const float*)d_in[7];
    const float* bv = (const float*)d_in[8];
    const float* Wo = (const float*)d_in[9];
    const float* bo = (const float*)d_in[10];
    const float* gamma = (const float*)d_in[11];
    const float* beta  = (const float*)d_in[12];

    char* ws = (char*)d_ws;
    const size_t MB = 1024 * 1024;
    unsigned short* qb  = (unsigned short*)(ws + 0);
    unsigned short* kb  = (unsigned short*)(ws + 8 * MB);
    unsigned short* vb  = (unsigned short*)(ws + 16 * MB);
    unsigned short* Wqt = (unsigned short*)(ws + 24 * MB);
    unsigned short* Wkt = (unsigned short*)(ws + 26 * MB);
    unsigned short* Wvt = (unsigned short*)(ws + 28 * MB);
    unsigned short* Wot = (unsigned short*)(ws + 30 * MB);
    unsigned short* Qp  = (unsigned short*)(ws + 32 * MB);
    unsigned short* Kp  = (unsigned short*)(ws + 40 * MB);
    unsigned short* Vtb = (unsigned short*)(ws + 48 * MB);
    unsigned short* att = (unsigned short*)(ws + 0);        // aliases qb (dead after Q-proj)
    float*          xbuf = (float*)(ws + 8 * MB);           // aliases kb+vb (dead after K/V-proj)

    prep_kernel<<<dim3(10240), 256, 0, stream>>>(query, key_, value, qb, kb, vb,
                                                 Wq, Wk, Wv, Wo, Wqt, Wkt, Wvt, Wot);

    gemm_qkv_kernel<<<dim3(32, 8, 3), 256, 0, stream>>>(qb, kb, vb, Wqt, Wkt, Wvt,
                                                        bq, bk, bv, Qp, Kp, Vtb);

    attn_kernel<<<dim3(512), 512, 0, stream>>>(Qp, Kp, Vtb, att);

    gemm_o_kernel<<<dim3(64, 8), 256, 0, stream>>>(att, Wot, bo, xbuf, query);
    ln_kernel<<<ROWS, 256, 0, stream>>>(xbuf, gamma, beta, (float*)d_out);
}

// Round 12
// 219.981 us; speedup vs baseline: 1.0333x; 1.0179x over previous
//
#include <hip/hip_runtime.h>

// ---------------- problem constants ----------------
#define EMBED 1024
#define NHEAD 16
#define HDIM  64
#define BATCH 2
#define SEQ   2048
#define ROWS  (BATCH*SEQ)   // 4096

typedef __bf16 bf16x8 __attribute__((ext_vector_type(8)));
typedef float  f32x4  __attribute__((ext_vector_type(4)));
typedef float  f32x16 __attribute__((ext_vector_type(16)));
typedef unsigned short u16x8 __attribute__((ext_vector_type(8)));
typedef unsigned short u16x4 __attribute__((ext_vector_type(4)));

__device__ __forceinline__ unsigned short f2bf(float f) {
    unsigned int u = __float_as_uint(f);
    u += 0x7FFFu + ((u >> 16) & 1u);          // round-to-nearest-even
    return (unsigned short)(u >> 16);
}
__device__ __forceinline__ f32x4 zero4() { f32x4 z = {0.f, 0.f, 0.f, 0.f}; return z; }

// pack two f32 -> bf16 pair in one instruction (RNE)
__device__ __forceinline__ unsigned int cvtpk_bf16(float lo, float hi) {
    unsigned int r;
    asm("v_cvt_pk_bf16_f32 %0, %1, %2" : "=v"(r) : "v"(lo), "v"(hi));
    return r;
}
// new_a = [a.row0 | b.row0], new_b = [a.row1 | b.row1]  (rows = lane<32 / lane>=32)
__device__ __forceinline__ void pl32swap(unsigned int &a, unsigned int &b) {
    asm("v_permlane32_swap_b32 %0, %1" : "+v"(a), "+v"(b));
}
// hardware exp2 (v_exp_f32: D = 2^S0)
__device__ __forceinline__ float exp2_hw(float x) {
    float r;
    asm("v_exp_f32 %0, %1" : "=v"(r) : "v"(x));
    return r;
}

// async global->LDS, 16B per lane; lds dest is wave-uniform base (+lane*16 by HW)
__device__ __forceinline__ void gl_lds16(const unsigned short* g, unsigned short* l) {
    __builtin_amdgcn_global_load_lds(
        (const __attribute__((address_space(1))) void*)g,
        (__attribute__((address_space(3))) void*)l, 16, 0, 0);
}

// ---------------- fused prep: f32->bf16 cast (q/k/v) + 4x weight transpose ------------
__global__ __launch_bounds__(256) void prep_kernel(
    const float* __restrict__ q, const float* __restrict__ k, const float* __restrict__ v,
    unsigned short* __restrict__ qo, unsigned short* __restrict__ ko,
    unsigned short* __restrict__ vo,
    const float* __restrict__ w0, const float* __restrict__ w1,
    const float* __restrict__ w2, const float* __restrict__ w3,
    unsigned short* __restrict__ o0, unsigned short* __restrict__ o1,
    unsigned short* __restrict__ o2, unsigned short* __restrict__ o3) {
    __shared__ float tile[32][33];
    const int bx = blockIdx.x, t = threadIdx.x;
    if (bx < 6144) {
        // cast: 8 f32 -> 8 bf16 per thread, 16B stores
        const float* in; unsigned short* out;
        int m = bx >> 11;                    // matrix 0..2
        int blk = bx & 2047;
        if (m == 0)      { in = q; out = qo; }
        else if (m == 1) { in = k; out = ko; }
        else             { in = v; out = vo; }
        int i = (blk * 256 + t) * 8;
        float4 a = *(const float4*)(in + i);
        float4 b = *(const float4*)(in + i + 4);
        u16x8 o = {f2bf(a.x), f2bf(a.y), f2bf(a.z), f2bf(a.w),
                   f2bf(b.x), f2bf(b.y), f2bf(b.z), f2bf(b.w)};
        *(u16x8*)(out + i) = o;
    } else {
        // W [K,N] f32 -> Wt [N,K] bf16, 32x32 tiles
        int idx = bx - 6144;
        int z = idx >> 10;                   // matrix 0..3
        int rem = idx & 1023;
        int bxx = rem & 31, byy = rem >> 5;
        const float* in; unsigned short* out;
        if (z == 0)      { in = w0; out = o0; }
        else if (z == 1) { in = w1; out = o1; }
        else if (z == 2) { in = w2; out = o2; }
        else             { in = w3; out = o3; }
        int tx = t & 31, ty = t >> 5;        // 32 x 8
        int x = bxx * 32 + tx;
        int y0 = byy * 32 + ty;
#pragma unroll
        for (int r = 0; r < 4; ++r)
            tile[ty + 8 * r][tx] = in[(size_t)(y0 + 8 * r) * EMBED + x];
        __syncthreads();
        int ox = byy * 32 + tx;
        int oy = bxx * 32 + ty;
#pragma unroll
        for (int r = 0; r < 4; ++r)
            out[(size_t)(oy + 8 * r) * EMBED + ox] = f2bf(tile[tx][ty + 8 * r]);
    }
}

// ---------------- 128x128 bf16 GEMM, ring-3 single-barrier K-loop ------
// R12: 512 threads / 8 waves (2x4 wave grid, 64x32 output per wave). Same tile,
// same ring-3 counted-vmcnt schedule, same LDS (48KB -> 3 blocks/CU), but
// 24 waves/CU (was 12) on an LDS-latency-bound inner loop. Stage = 2 gl_lds
// per wave (512 lanes cover a full 8KB tile per instruction); vmcnt 4 -> 2.
__global__ __launch_bounds__(512, 4) void gemm_qkv_kernel(
    const unsigned short* __restrict__ qb, const unsigned short* __restrict__ kb,
    const unsigned short* __restrict__ vb,
    const unsigned short* __restrict__ Wqt, const unsigned short* __restrict__ Wkt,
    const unsigned short* __restrict__ Wvt,
    const float* __restrict__ bq, const float* __restrict__ bk, const float* __restrict__ bv,
    unsigned short* __restrict__ Qp, unsigned short* __restrict__ Kp,
    unsigned short* __restrict__ Vtb) {
    __shared__ unsigned short smem[24576];   // A slots [0,12288) x3, B slots [12288,24576) x3
                                             // epilogue: reused as 64x136 transpose tile
    const unsigned short *A, *Bt; const float* bias; unsigned short* outp; int mode; float osc;
    if (blockIdx.z == 0)      { A = qb; Bt = Wqt; bias = bq; outp = Qp;  mode = 0; osc = 0.18033688f; }
    else if (blockIdx.z == 1) { A = kb; Bt = Wkt; bias = bk; outp = Kp;  mode = 0; osc = 1.0f; }
    else                      { A = vb; Bt = Wvt; bias = bv; outp = Vtb; mode = 1; osc = 1.0f; }

    const int t = threadIdx.x;               // 0..511
    const int m0 = blockIdx.x * 128, n0 = blockIdx.y * 128;
    const int wave = t >> 6, lane = t & 63;
    const int wr = wave >> 2, wc = wave & 3;             // 2x4 wave grid, 64x32 each
    const int lm = lane & 15, lq = lane >> 4;
    const int sr = t >> 2;                               // staging row 0..127
    const int csrc = (t & 3) ^ ((sr >> 1) & 3);          // chunk-XOR swizzle source
    const int pa = lq ^ ((lm >> 1) & 3);                 // fragment chunk position

    const unsigned short* gA = A + (size_t)(m0 + sr) * EMBED + csrc * 8;
    const unsigned short* gB = Bt + (size_t)(n0 + sr) * EMBED + csrc * 8;

    f32x4 acc[4][2];
#pragma unroll
    for (int i = 0; i < 4; ++i)
#pragma unroll
        for (int j = 0; j < 2; ++j) acc[i][j] = zero4();

#define QKV_STAGE(SOFF)                                                      \
    gl_lds16(gA, smem + (SOFF) + wave * 512);                                \
    gl_lds16(gB, smem + 12288 + (SOFF) + wave * 512);                        \
    gA += 32; gB += 32;

#define QKV_COMP(COFF)                                                                 \
    {                                                                                  \
        bf16x8 af[4], bfr[2];                                                          \
        _Pragma("unroll")                                                              \
        for (int i = 0; i < 4; ++i)                                                    \
            af[i] = *(const bf16x8*)&smem[(COFF) + (wr * 64 + i * 16 + lm) * 32 + pa * 8]; \
        _Pragma("unroll")                                                              \
        for (int j = 0; j < 2; ++j)                                                    \
            bfr[j] = *(const bf16x8*)&smem[12288 + (COFF) + (wc * 32 + j * 16 + lm) * 32 + pa * 8]; \
        _Pragma("unroll")                                                              \
        for (int i = 0; i < 4; ++i)                                                    \
            _Pragma("unroll")                                                          \
            for (int j = 0; j < 2; ++j)                                                \
                acc[i][j] = __builtin_amdgcn_mfma_f32_16x16x32_bf16(af[i], bfr[j], acc[i][j], 0, 0, 0); \
    }

    // prologue: tile0 -> slot0, tile1 -> slot1; ptrs end at tile2
    QKV_STAGE(0)
    QKV_STAGE(4096)

    for (int g = 0; g < 10; ++g) {       // i = 3g, 3g+1, 3g+2  (covers 0..29)
        asm volatile("s_waitcnt vmcnt(2)" ::: "memory");
        __builtin_amdgcn_s_barrier();
        QKV_STAGE(8192)                  // tile i+2 -> slot2
        QKV_COMP(0)
        asm volatile("s_waitcnt vmcnt(2)" ::: "memory");
        __builtin_amdgcn_s_barrier();
        QKV_STAGE(0)                     // -> slot0
        QKV_COMP(4096)
        asm volatile("s_waitcnt vmcnt(2)" ::: "memory");
        __builtin_amdgcn_s_barrier();
        QKV_STAGE(4096)                  // -> slot1
        QKV_COMP(8192)
    }
    // i=30 (slot0, no stage), i=31 (slot1, drain)
    asm volatile("s_waitcnt vmcnt(2)" ::: "memory");
    __builtin_amdgcn_s_barrier();
    QKV_COMP(0)
    asm volatile("s_waitcnt vmcnt(0)" ::: "memory");
    __builtin_amdgcn_s_barrier();
    QKV_COMP(4096)

    const int row = t >> 3, seg = t & 7;     // readback: 32B per thread, coalesced
    if (mode == 0) {
        // out[s][hd]: two passes over m-halves; LDS tile Ct[ml 64][nl 128] (+8 pad)
#pragma unroll
        for (int p = 0; p < 2; ++p) {
            __syncthreads();
            if (wr == p) {
#pragma unroll
                for (int i = 0; i < 4; ++i)
#pragma unroll
                    for (int j = 0; j < 2; ++j) {
                        float bn = bias[n0 + wc * 32 + j * 16 + lm];
                        int nl = wc * 32 + j * 16 + lm;
#pragma unroll
                        for (int r = 0; r < 4; ++r)
                            smem[(i * 16 + lq * 4 + r) * 136 + nl] =
                                f2bf((acc[i][j][r] + bn) * osc);
                    }
            }
            __syncthreads();
            int m = m0 + p * 64 + row;
            int b = m >> 11, sI = m & 2047;
            int ncol = n0 + seg * 16;
            int h = ncol >> 6, hd0 = ncol & 63;
            unsigned short* dst = outp + (((size_t)((b * NHEAD + h) * SEQ + sI)) << 6) + hd0;
            const unsigned short* src = smem + row * 136 + seg * 16;
            *(u16x8*)(dst)     = *(const u16x8*)(src);
            *(u16x8*)(dst + 8) = *(const u16x8*)(src + 8);
        }
    } else {
        // out[hd][s]: two passes over n-halves; LDS tile Cn[nl 64][ml 128] (+8 pad), packed writes
#pragma unroll
        for (int p = 0; p < 2; ++p) {
            __syncthreads();
            if ((wc >> 1) == p) {
#pragma unroll
                for (int i = 0; i < 4; ++i)
#pragma unroll
                    for (int j = 0; j < 2; ++j) {
                        float bn = bias[n0 + p * 64 + (wc & 1) * 32 + j * 16 + lm];
                        int nl = (wc & 1) * 32 + j * 16 + lm;
                        u16x4 pw = {f2bf(acc[i][j][0] + bn), f2bf(acc[i][j][1] + bn),
                                    f2bf(acc[i][j][2] + bn), f2bf(acc[i][j][3] + bn)};
                        *(u16x4*)&smem[nl * 136 + wr * 64 + i * 16 + lq * 4] = pw;
                    }
            }
            __syncthreads();
            int n = n0 + p * 64 + row;
            int h = n >> 6, hd = n & 63;
            int b = m0 >> 11;
            int s0 = (m0 & 2047) + seg * 16;
            unsigned short* dst = outp + ((size_t)((b * NHEAD + h) * HDIM + hd)) * SEQ + s0;
            const unsigned short* src = smem + row * 136 + seg * 16;
            *(u16x8*)(dst)     = *(const u16x8*)(src);
            *(u16x8*)(dst + 8) = *(const u16x8*)(src + 8);
        }
    }
#undef QKV_STAGE
#undef QKV_COMP
}

// ---------------- O-projection GEMM: M64 x N128 tiles, ring-3 single-barrier (R8 form) ----
__global__ __launch_bounds__(256, 2) void gemm_o_kernel(
    const unsigned short* __restrict__ att, const unsigned short* __restrict__ Wot,
    const float* __restrict__ bo, float* __restrict__ xbuf,
    const float* __restrict__ residual) {
    __shared__ unsigned short smem[18432];   // A slots [0,6144) x3 (2048 each), B slots [6144,18432) x3 (4096 each)
    const int t = threadIdx.x;
    const int m0 = blockIdx.x * 64, n0 = blockIdx.y * 128;
    const int wave = t >> 6, lane = t & 63;
    const int lm = lane & 15, lq = lane >> 4;
    const int sr = t >> 2;
    const int csrc = (t & 3) ^ ((sr >> 1) & 3);
    const int pa = lq ^ ((lm >> 1) & 3);

    const unsigned short* gA = att + (size_t)(m0 + sr) * EMBED + csrc * 8;
    const unsigned short* gB = Wot + (size_t)(n0 + sr) * EMBED + csrc * 8;

    f32x4 acc[4][2];
#pragma unroll
    for (int i = 0; i < 4; ++i)
#pragma unroll
        for (int j = 0; j < 2; ++j) acc[i][j] = zero4();

#define O_STAGE(SA, SB)                                                  \
    gl_lds16(gA,              smem + (SA) + wave * 512);                 \
    gl_lds16(gB,              smem + 6144 + (SB) + wave * 512);          \
    gl_lds16(gB + 64 * EMBED, smem + 6144 + (SB) + 2048 + wave * 512);   \
    gA += 32; gB += 32;

#define O_COMP(SA, SB)                                                                \
    {                                                                                 \
        bf16x8 af[4], bfr[2];                                                         \
        _Pragma("unroll")                                                             \
        for (int i = 0; i < 4; ++i)                                                   \
            af[i] = *(const bf16x8*)&smem[(SA) + (i * 16 + lm) * 32 + pa * 8];        \
        _Pragma("unroll")                                                             \
        for (int j = 0; j < 2; ++j)                                                   \
            bfr[j] = *(const bf16x8*)&smem[6144 + (SB) + (wave * 32 + j * 16 + lm) * 32 + pa * 8]; \
        _Pragma("unroll")                                                             \
        for (int i = 0; i < 4; ++i)                                                   \
            _Pragma("unroll")                                                         \
            for (int j = 0; j < 2; ++j)                                               \
                acc[i][j] = __builtin_amdgcn_mfma_f32_16x16x32_bf16(af[i], bfr[j], acc[i][j], 0, 0, 0); \
    }

    // prologue: tile0 -> slot0, tile1 -> slot1
    O_STAGE(0, 0)
    O_STAGE(2048, 4096)

    for (int g = 0; g < 10; ++g) {
        asm volatile("s_waitcnt vmcnt(3)" ::: "memory");
        __builtin_amdgcn_s_barrier();
        O_STAGE(4096, 8192)
        O_COMP(0, 0)
        asm volatile("s_waitcnt vmcnt(3)" ::: "memory");
        __builtin_amdgcn_s_barrier();
        O_STAGE(0, 0)
        O_COMP(2048, 4096)
        asm volatile("s_waitcnt vmcnt(3)" ::: "memory");
        __builtin_amdgcn_s_barrier();
        O_STAGE(2048, 4096)
        O_COMP(4096, 8192)
    }
    asm volatile("s_waitcnt vmcnt(3)" ::: "memory");
    __builtin_amdgcn_s_barrier();
    O_COMP(0, 0)
    asm volatile("s_waitcnt vmcnt(0)" ::: "memory");
    __builtin_amdgcn_s_barrier();
    O_COMP(2048, 4096)

#pragma unroll
    for (int i = 0; i < 4; ++i)
#pragma unroll
        for (int j = 0; j < 2; ++j) {
            int n = n0 + wave * 32 + j * 16 + lm;
            float bn = bo[n];
#pragma unroll
            for (int r = 0; r < 4; ++r) {
                int m = m0 + i * 16 + lq * 4 + r;
                size_t idx = (size_t)m * EMBED + n;
                xbuf[idx] = acc[i][j][r] + bn + residual[idx];
            }
        }
#undef O_STAGE
#undef O_COMP
}

// ---------------- flash attention (R11 structure, unchanged) ----------------
__global__ __launch_bounds__(512, 4) void attn_kernel(const unsigned short* __restrict__ Qp,
                                                      const unsigned short* __restrict__ Kp,
                                                      const unsigned short* __restrict__ Vt,
                                                      unsigned short* __restrict__ att) {
    __shared__ unsigned short KV[32768];     // [0,16384): K [buf2][tile2][4096] ; [16384,32768): V
                                             // epilogue: f32 merge buffer [128][68] + l[128]
    unsigned short* Ks = KV;
    unsigned short* Vs = KV + 16384;
    const int t = threadIdx.x;               // 0..511
    const int bx = blockIdx.x;
    const int bh = bx & 31;                  // XCD-stable: same-head blocks differ by 32
    const int b = bh >> 4, h = bh & 15;
    const int q0 = (bx >> 5) * 128;
    const unsigned short* Qh = Qp + (size_t)bh * SEQ * HDIM;
    const unsigned short* Kh = Kp + (size_t)bh * SEQ * HDIM;
    const unsigned short* Vh = Vt + (size_t)bh * HDIM * SEQ;
    const int wave = t >> 6, lane = t & 63;
    const int g = wave >> 2, ws = wave & 3;  // kv-parity group / q-slice
    const int ln31 = lane & 31, halfl = lane >> 5;

    bf16x8 qf[4];
    {
        const unsigned short* qptr = Qh + (size_t)(q0 + ws * 32 + ln31) * HDIM + halfl * 8;
#pragma unroll
        for (int s = 0; s < 4; ++s) qf[s] = *(const bf16x8*)(qptr + s * 16);
    }

    // pair staging: 512 threads cover 2 tiles x 512 chunks
    const int f0 = t >> 6, m0_ = t & 31, hh0 = (t >> 5) & 1;
    const unsigned short* gK0 = Kh + (size_t)((f0 >> 2) * 32 + m0_) * HDIM + (f0 & 3) * 16 + hh0 * 8;
    const unsigned short* gV0 = Vh + (size_t)((f0 >> 2) * 32 + m0_) * SEQ + (f0 & 3) * 16 + hh0 * 8;

#define ATTN_STAGE(NBO)                                                   \
    gl_lds16(gK0,             Ks + (NBO) + wave * 512);                   \
    gl_lds16(gK0 + 64 * HDIM, Ks + (NBO) + 4096 + wave * 512);            \
    gl_lds16(gV0,             Vs + (NBO) + wave * 512);                   \
    gl_lds16(gV0 + 64,        Vs + (NBO) + 4096 + wave * 512);            \
    gK0 += 128 * HDIM; gV0 += 128;

    // prologue: pair0 -> buf0, pair1 -> buf1 (8 loads in flight); ptrs end at pair2
    ATTN_STAGE(0)
    ATTN_STAGE(8192)

    // persistent exp-offset vector: C-operand of the first QK MFMA of every chain
    f32x16 OFFS;
#pragma unroll
    for (int r = 0; r < 16; ++r) OFFS[r] = -17.312340f;   // -12*log2(e)

    f32x16 Oa[2];
#pragma unroll
    for (int mo = 0; mo < 2; ++mo)
#pragma unroll
        for (int r = 0; r < 16; ++r) Oa[mo][r] = 0.f;
    float rpA = 0.f, rpB = 0.f, rpC = 0.f, rpD = 0.f;

    for (int kt = 0; kt < 16; ++kt) {
        // wait for pair kt only: 4 newer loads (pair kt+1) stay in flight
        if (kt < 15) { asm volatile("s_waitcnt vmcnt(4)" ::: "memory"); }
        else         { asm volatile("s_waitcnt vmcnt(0)" ::: "memory"); }
        __builtin_amdgcn_s_barrier();
        const int cbo = (kt & 1) * 8192 + g * 4096;   // this group's tile of the pair

        // QK for BOTH mt halves first
        f32x16 S0, S1;
        __builtin_amdgcn_s_setprio(1);
        {
            bf16x8 af = *(const bf16x8*)&Ks[cbo + halfl * 256 + ln31 * 8];
            S0 = __builtin_amdgcn_mfma_f32_32x32x16_bf16(af, qf[0], OFFS, 0, 0, 0);
        }
#pragma unroll
        for (int s = 1; s < 4; ++s) {
            bf16x8 af = *(const bf16x8*)&Ks[cbo + s * 512 + halfl * 256 + ln31 * 8];
            S0 = __builtin_amdgcn_mfma_f32_32x32x16_bf16(af, qf[s], S0, 0, 0, 0);
        }
        {
            bf16x8 af = *(const bf16x8*)&Ks[cbo + 4 * 512 + halfl * 256 + ln31 * 8];
            S1 = __builtin_amdgcn_mfma_f32_32x32x16_bf16(af, qf[0], OFFS, 0, 0, 0);
        }
#pragma unroll
        for (int s = 1; s < 4; ++s) {
            bf16x8 af = *(const bf16x8*)&Ks[cbo + (4 + s) * 512 + halfl * 256 + ln31 * 8];
            S1 = __builtin_amdgcn_mfma_f32_32x32x16_bf16(af, qf[s], S1, 0, 0, 0);
        }
        __builtin_amdgcn_s_setprio(0);

        // SM+PV per mt; SM(S1) is independent of PV(S0) -> dual-pipe overlap
#define SMPV(S, MT)                                                               \
        {                                                                         \
            _Pragma("unroll")                                                     \
            for (int rg = 0; rg < 4; ++rg) {                                      \
                float p0 = exp2_hw(S[rg * 4 + 0]);                                \
                float p1 = exp2_hw(S[rg * 4 + 1]);                                \
                float p2 = exp2_hw(S[rg * 4 + 2]);                                \
                float p3 = exp2_hw(S[rg * 4 + 3]);                                \
                S[rg * 4 + 0] = p0; rpA += p0;                                    \
                S[rg * 4 + 1] = p1; rpB += p1;                                    \
                S[rg * 4 + 2] = p2; rpC += p2;                                    \
                S[rg * 4 + 3] = p3; rpD += p3;                                    \
            }                                                                     \
            __builtin_amdgcn_s_setprio(1);                                        \
            _Pragma("unroll")                                                     \
            for (int p = 0; p < 2; ++p) {                                         \
                unsigned int a0 = cvtpk_bf16(S[8 * p + 0], S[8 * p + 1]);         \
                unsigned int a1 = cvtpk_bf16(S[8 * p + 2], S[8 * p + 3]);         \
                unsigned int b0 = cvtpk_bf16(S[8 * p + 4], S[8 * p + 5]);         \
                unsigned int b1 = cvtpk_bf16(S[8 * p + 6], S[8 * p + 7]);         \
                pl32swap(a0, b0);                                                 \
                pl32swap(a1, b1);                                                 \
                union { unsigned int u[4]; bf16x8 v; } bp;                        \
                bp.u[0] = a0; bp.u[1] = a1; bp.u[2] = b0; bp.u[3] = b1;           \
                const int sp = (MT) * 2 + p;                                      \
                _Pragma("unroll")                                                 \
                for (int mo = 0; mo < 2; ++mo) {                                  \
                    bf16x8 av = *(const bf16x8*)&Vs[cbo + (mo * 4 + sp) * 512 + halfl * 256 + ln31 * 8]; \
                    Oa[mo] = __builtin_amdgcn_mfma_f32_32x32x16_bf16(av, bp.v, Oa[mo], 0, 0, 0); \
                }                                                                 \
            }                                                                     \
            __builtin_amdgcn_s_setprio(0);                                        \
        }

        SMPV(S0, 0)
        SMPV(S1, 1)
#undef SMPV

        if (kt < 14) {
            __builtin_amdgcn_s_barrier();   // all waves done reading buf cur
            const int nbo = (kt & 1) * 8192;
            ATTN_STAGE(nbo)                 // pair kt+2 -> buf cur; stays in flight
        }
    }
#undef ATTN_STAGE

    // per-q sum over this group's kv range (lane halves cover disjoint kv rows)
    float lsum = (rpA + rpB) + (rpC + rpD);
    unsigned int la = __float_as_uint(lsum), lb = __float_as_uint(lsum);
    pl32swap(la, lb);
    float ltot = __uint_as_float(la) + __uint_as_float(lb);

    // in-LDS merge of the two kv-parity groups (f32, exact)
    __syncthreads();                        // all K/V ds_reads complete; LDS reusable
    float* shO = (float*)KV;                // [128][68] padded
    float* shL = (float*)KV + 128 * 68;
    const int qr = ws * 32 + ln31;
    if (g == 1) {
#pragma unroll
        for (int mo = 0; mo < 2; ++mo)
#pragma unroll
            for (int rg = 0; rg < 4; ++rg) {
                float4 v;
                v.x = Oa[mo][rg * 4 + 0]; v.y = Oa[mo][rg * 4 + 1];
                v.z = Oa[mo][rg * 4 + 2]; v.w = Oa[mo][rg * 4 + 3];
                *(float4*)&shO[qr * 68 + mo * 32 + rg * 8 + halfl * 4] = v;
            }
        shL[qr] = ltot;
    }
    __syncthreads();
    if (g == 0) {
        float inv = 1.f / (ltot + shL[qr]);
        unsigned short* orow = att + (size_t)(b * SEQ + q0 + qr) * EMBED + h * HDIM;
#pragma unroll
        for (int mo = 0; mo < 2; ++mo)
#pragma unroll
            for (int rg = 0; rg < 4; ++rg) {
                float4 v = *(const float4*)&shO[qr * 68 + mo * 32 + rg * 8 + halfl * 4];
                u16x4 ow = {f2bf((Oa[mo][rg * 4 + 0] + v.x) * inv),
                            f2bf((Oa[mo][rg * 4 + 1] + v.y) * inv),
                            f2bf((Oa[mo][rg * 4 + 2] + v.z) * inv),
                            f2bf((Oa[mo][rg * 4 + 3] + v.w) * inv)};
                *(u16x4*)&orow[mo * 32 + rg * 8 + halfl * 4] = ow;
            }
    }
}

// ---------------- row LayerNorm (one block per row) ----------------
__global__ __launch_bounds__(256) void ln_kernel(const float* __restrict__ x,
                                                 const float* __restrict__ gamma,
                                                 const float* __restrict__ beta,
                                                 float* __restrict__ out) {
    __shared__ float red[8];
    const int row = blockIdx.x, t = threadIdx.x;
    float4 v = *(const float4*)(x + (size_t)row * EMBED + t * 4);
    float s = v.x + v.y + v.z + v.w;
    float ss = v.x * v.x + v.y * v.y + v.z * v.z + v.w * v.w;
#pragma unroll
    for (int o = 1; o < 64; o <<= 1) {
        s += __shfl_xor(s, o);
        ss += __shfl_xor(ss, o);
    }
    int wave = t >> 6, lane = t & 63;
    if (lane == 0) { red[wave] = s; red[4 + wave] = ss; }
    __syncthreads();
    s = red[0] + red[1] + red[2] + red[3];
    ss = red[4] + red[5] + red[6] + red[7];
    float mu = s * (1.f / EMBED);
    float var = ss * (1.f / EMBED) - mu * mu;
    float rstd = rsqrtf(var + 1e-5f);
    float4 g = *(const float4*)(gamma + t * 4);
    float4 bb = *(const float4*)(beta + t * 4);
    float4 o;
    o.x = (v.x - mu) * rstd * g.x + bb.x;
    o.y = (v.y - mu) * rstd * g.y + bb.y;
    o.z = (v.z - mu) * rstd * g.z + bb.z;
    o.w = (v.w - mu) * rstd * g.w + bb.w;
    *(float4*)(out + (size_t)row * EMBED + t * 4) = o;
}

// ---------------- launch ----------------
extern "C" void kernel_launch(void* const* d_in, const int* in_sizes, int n_in,
                              void* d_out, int out_size, void* d_ws, size_t ws_size,
                              hipStream_t stream) {
    const float* query = (const float*)d_in[0];
    const float* key_  = (const float*)d_in[1];
    const float* value = (const float*)d_in[2];
    const float* Wq = (const float*)d_in[3];
    const float* bq = (const float*)d_in[4];
    const float* Wk = (const float*)d_in[5];
    const float* bk = (const float*)d_in[6];
    const float* Wv = (const float*)d_in[7];
    const float* bv = (const float*)d_in[8];
    const float* Wo = (const float*)d_in[9];
    const float* bo = (const float*)d_in[10];
    const float* gamma = (const float*)d_in[11];
    const float* beta  = (const float*)d_in[12];

    char* ws = (char*)d_ws;
    const size_t MB = 1024 * 1024;
    unsigned short* qb  = (unsigned short*)(ws + 0);
    unsigned short* kb  = (unsigned short*)(ws + 8 * MB);
    unsigned short* vb  = (unsigned short*)(ws + 16 * MB);
    unsigned short* Wqt = (unsigned short*)(ws + 24 * MB);
    unsigned short* Wkt = (unsigned short*)(ws + 26 * MB);
    unsigned short* Wvt = (unsigned short*)(ws + 28 * MB);
    unsigned short* Wot = (unsigned short*)(ws + 30 * MB);
    unsigned short* Qp  = (unsigned short*)(ws + 32 * MB);
    unsigned short* Kp  = (unsigned short*)(ws + 40 * MB);
    unsigned short* Vtb = (unsigned short*)(ws + 48 * MB);
    unsigned short* att = (unsigned short*)(ws + 0);        // aliases qb (dead after Q-proj)
    float*          xbuf = (float*)(ws + 8 * MB);           // aliases kb+vb (dead after K/V-proj)

    prep_kernel<<<dim3(10240), 256, 0, stream>>>(query, key_, value, qb, kb, vb,
                                                 Wq, Wk, Wv, Wo, Wqt, Wkt, Wvt, Wot);

    gemm_qkv_kernel<<<dim3(32, 8, 3), 512, 0, stream>>>(qb, kb, vb, Wqt, Wkt, Wvt,
                                                        bq, bk, bv, Qp, Kp, Vtb);

    attn_kernel<<<dim3(512), 512, 0, stream>>>(Qp, Kp, Vtb, att);

    gemm_o_kernel<<<dim3(64, 8), 256, 0, stream>>>(att, Wot, bo, xbuf, query);
    ln_kernel<<<ROWS, 256, 0, stream>>>(xbuf, gamma, beta, (float*)d_out);
}